// Round 3
// baseline (979.191 us; speedup 1.0000x reference)
//
#include <hip/hip_runtime.h>
#include <hip/hip_bf16.h>

using short8 = __attribute__((ext_vector_type(8))) short;
using f32x16 = __attribute__((ext_vector_type(16))) float;
using us4    = __attribute__((ext_vector_type(4))) unsigned short;

#define NHID 15872
#define NCLS 32

__device__ __forceinline__ unsigned short f2bf(float f) {
  unsigned u = __builtin_bit_cast(unsigned, f);
  u += 0x7fff + ((u >> 16) & 1);          // RNE
  return (unsigned short)(u >> 16);
}
__device__ __forceinline__ unsigned short f2bf_hw(float f) {
  __hip_bfloat16 h = __float2bfloat16(f); // HW v_cvt (RNE), compiler pairs into cvt_pk
  return __builtin_bit_cast(unsigned short, h);
}
__device__ __forceinline__ float bf2f(unsigned short h) {
  return __builtin_bit_cast(float, ((unsigned)h) << 16);
}

// ---------------- kernel 0: x fp32 -> bf16 ----------------
__global__ void cvt_x(const float* __restrict__ x, unsigned short* __restrict__ xb) {
  int i = (blockIdx.x * 256 + threadIdx.x) * 4;
  float4 v = *reinterpret_cast<const float4*>(x + i);
  us4 o;
  o[0] = f2bf(v.x); o[1] = f2bf(v.y); o[2] = f2bf(v.z); o[3] = f2bf(v.w);
  *reinterpret_cast<us4*>(xb + i) = o;
}

// ---------------- main GEMM: C_bf16[256][15872] = relu(A_bf16 @ B_f32 + bias) ----------------
// No LDS, no barriers: pure streaming. grid = 248 (N tiles of 64), block = 512
// (8 waves: 4M x 2N). Each lane loads its B-column k-slices directly from
// global (coalesced 256B wave-wide) and converts f32->bf16 in-register.
__global__ __launch_bounds__(512, 2)
void gemm_stream(const unsigned short* __restrict__ A, int lda, int K,
                 const float* __restrict__ B, const float* __restrict__ bias,
                 unsigned short* __restrict__ C)
{
  const int tid  = threadIdx.x;
  const int n0   = blockIdx.x * 64;
  const int lane = tid & 63;
  const int w    = tid >> 6;
  const int wm   = w >> 1;     // 0..3 -> 64 rows each
  const int wn   = w & 1;      // 0..1 -> 32 cols each
  const int l31  = lane & 31;
  const int hi   = lane >> 5;

  f32x16 acc0 = {0.f,0.f,0.f,0.f,0.f,0.f,0.f,0.f,0.f,0.f,0.f,0.f,0.f,0.f,0.f,0.f};
  f32x16 acc1 = acc0;

  // A: lane supplies row (wm*64+l31), k-bytes at hi*8
  const unsigned short* abase = A + (size_t)(wm * 64 + l31) * lda + hi * 8;
  // B: lane supplies col (n0+wn*32+l31), k = kk*16 + hi*8 + j
  const float* bbase = B + (size_t)hi * 8 * NHID + n0 + wn * 32 + l31;

  const int NT = K >> 6;
  for (int t = 0; t < NT; ++t) {
    const unsigned short* at = abase + (size_t)t * 64;
    const float* bt = bbase + (size_t)t * 64 * NHID;
#pragma unroll
    for (int kk = 0; kk < 4; ++kk) {
      short8 a0 = *reinterpret_cast<const short8*>(at + kk * 16);
      short8 a1 = *reinterpret_cast<const short8*>(at + (size_t)32 * lda + kk * 16);
      const float* bp = bt + (size_t)kk * 16 * NHID;
      float bf[8];
#pragma unroll
      for (int j = 0; j < 8; ++j) bf[j] = bp[(size_t)j * NHID];
      short8 bv;
#pragma unroll
      for (int j = 0; j < 8; ++j) bv[j] = (short)f2bf_hw(bf[j]);
      acc0 = __builtin_amdgcn_mfma_f32_32x32x16_bf16(a0, bv, acc0, 0, 0, 0);
      acc1 = __builtin_amdgcn_mfma_f32_32x32x16_bf16(a1, bv, acc1, 0, 0, 0);
    }
  }

  // epilogue: bias + relu + bf16 store (verified layout from round 2)
  const int col = n0 + wn * 32 + l31;
  const float bvs = bias[col];
#pragma unroll
  for (int reg = 0; reg < 16; ++reg) {
    int rowoff = (reg & 3) + 8 * (reg >> 2) + 4 * hi;
    {
      int row = wm * 64 + rowoff;
      float v = acc0[reg] + bvs; v = v > 0.f ? v : 0.f;
      C[(size_t)row * NHID + col] = f2bf(v);
    }
    {
      int row = wm * 64 + 32 + rowoff;
      float v = acc1[reg] + bvs; v = v > 0.f ? v : 0.f;
      C[(size_t)row * NHID + col] = f2bf(v);
    }
  }
}

// ---------------- kernel: fold Wout [15872][992] -> Wv [15872][32] ----------------
__global__ void wv_fold(const float* __restrict__ Wout, float* __restrict__ Wv) {
  int g = blockIdx.x * 256 + threadIdx.x;   // < 15872*32
  int k = g >> 5, c = g & 31;
  const float* row = Wout + (size_t)k * 992;
  float s = 0.f;
#pragma unroll
  for (int o = 0; o < 32; ++o) {
    if (o == c) continue;
    int i = c < o ? c : o;
    int j = c < o ? o : c;
    int p = 31 * i - (i * (i - 1)) / 2 + (j - i - 1);
    s += row[2 * p + (c > o ? 1 : 0)];
  }
  Wv[g] = s;
}

// ---------------- kernel: votes partial = h2 @ Wv, K-split 32 ----------------
__global__ void votes_partial(const unsigned short* __restrict__ h2,
                              const float* __restrict__ Wv,
                              float* __restrict__ part) {
  int bm = blockIdx.x >> 5;        // 0..31 -> 8 rows each
  int ks = blockIdx.x & 31;        // K split
  int r  = bm * 8 + (threadIdx.x >> 5);
  int c  = threadIdx.x & 31;
  const unsigned short* hrow = h2 + (size_t)r * NHID + ks * 496;
  const float* wp = Wv + (size_t)(ks * 496) * 32 + c;
  float s = 0.f;
  for (int k0 = 0; k0 < 496; k0 += 8) {
    short8 hv = *reinterpret_cast<const short8*>(hrow + k0);
#pragma unroll
    for (int j = 0; j < 8; ++j)
      s += bf2f((unsigned short)hv[j]) * wp[(size_t)(k0 + j) * 32];
  }
  part[(size_t)(ks * 256 + r) * 32 + c] = s;
}

// ---------------- kernel: reduce partials + bias-fold ----------------
__global__ void votes_reduce(const float* __restrict__ part,
                             const float* __restrict__ bout,
                             float* __restrict__ out) {
  int g = blockIdx.x * 256 + threadIdx.x;  // < 8192
  int c = g & 31;
  float s = 0.f;
#pragma unroll
  for (int ks = 0; ks < 32; ++ks) s += part[(size_t)ks * 8192 + g];
  float bv = 0.f;
#pragma unroll
  for (int o = 0; o < 32; ++o) {
    if (o == c) continue;
    int i = c < o ? c : o;
    int j = c < o ? o : c;
    int p = 31 * i - (i * (i - 1)) / 2 + (j - i - 1);
    bv += bout[2 * p + (c > o ? 1 : 0)];
  }
  out[g] = s + bv;
}

extern "C" void kernel_launch(void* const* d_in, const int* in_sizes, int n_in,
                              void* d_out, int out_size, void* d_ws, size_t ws_size,
                              hipStream_t stream) {
  const float* x    = (const float*)d_in[0];
  const float* W1   = (const float*)d_in[1];
  const float* b1   = (const float*)d_in[2];
  const float* W2   = (const float*)d_in[3];
  const float* b2   = (const float*)d_in[4];
  const float* Wout = (const float*)d_in[5];
  const float* bout = (const float*)d_in[6];
  float* out = (float*)d_out;

  char* ws = (char*)d_ws;
  unsigned short* xb = (unsigned short*)(ws);                       // 256*512*2   = 262144
  unsigned short* h1 = (unsigned short*)(ws + 262144);              // 256*15872*2 = 8126464
  unsigned short* h2 = (unsigned short*)(ws + 8388608);             // 8126464
  float*          Wv = (float*)(ws + 16515072);                     // 15872*32*4  = 2031616
  float*        part = (float*)(ws + 18546688);                     // 32*256*32*4 = 1048576

  hipLaunchKernelGGL(cvt_x,         dim3(128),  dim3(256), 0, stream, x, xb);
  hipLaunchKernelGGL(gemm_stream,   dim3(248),  dim3(512), 0, stream, xb, 512, 512, W1, b1, h1);
  hipLaunchKernelGGL(gemm_stream,   dim3(248),  dim3(512), 0, stream, h1, NHID, NHID, W2, b2, h2);
  hipLaunchKernelGGL(wv_fold,       dim3(1984), dim3(256), 0, stream, Wout, Wv);
  hipLaunchKernelGGL(votes_partial, dim3(1024), dim3(256), 0, stream, h2, Wv, part);
  hipLaunchKernelGGL(votes_reduce,  dim3(32),   dim3(256), 0, stream, part, bout, out);
}

// Round 4
// 794.209 us; speedup vs baseline: 1.2329x; 1.2329x over previous
//
#include <hip/hip_runtime.h>
#include <hip/hip_bf16.h>

using short8 = __attribute__((ext_vector_type(8))) short;
using f32x16 = __attribute__((ext_vector_type(16))) float;
using us4    = __attribute__((ext_vector_type(4))) unsigned short;

#define NHID 15872
#define NCLS 32

__device__ __forceinline__ unsigned short f2bf(float f) {
  unsigned u = __builtin_bit_cast(unsigned, f);
  u += 0x7fff + ((u >> 16) & 1);          // RNE
  return (unsigned short)(u >> 16);
}
__device__ __forceinline__ float bf2f(unsigned short h) {
  return __builtin_bit_cast(float, ((unsigned)h) << 16);
}

// ---------------- kernel 0: x fp32 -> bf16 ----------------
__global__ void cvt_x(const float* __restrict__ x, unsigned short* __restrict__ xb) {
  int i = (blockIdx.x * 256 + threadIdx.x) * 4;
  float4 v = *reinterpret_cast<const float4*>(x + i);
  us4 o;
  o[0] = f2bf(v.x); o[1] = f2bf(v.y); o[2] = f2bf(v.z); o[3] = f2bf(v.w);
  *reinterpret_cast<us4*>(xb + i) = o;
}

// ---------------- main GEMM, K-split ----------------
// C[256][NHID] (+bias,relu -> bf16) or fp32 partials per K-chunk.
// grid = (248 N-tiles, S K-chunks), block = 512 (8 waves: 4M x 2N), BK=64.
template<bool FINAL>
__global__ __launch_bounds__(512, 2)
void gemm_k(const unsigned short* __restrict__ A, int lda, int KC,
            const float* __restrict__ B, const float* __restrict__ bias,
            unsigned short* __restrict__ Cf, float* __restrict__ Cp)
{
  __shared__ short Blds[2][64 * 64];   // [buf][col][k] bf16, 16B-chunk swizzled
  const int tid  = threadIdx.x;
  const int n0   = blockIdx.x * 64;
  const int ks   = blockIdx.y;
  const int k0   = ks * KC;
  const int lane = tid & 63;
  const int w    = tid >> 6;
  const int wm   = w >> 1;     // 0..3 -> 64 rows each
  const int wn   = w & 1;      // 0..1 -> 32 cols each
  const int l31  = lane & 31;
  const int hi   = lane >> 5;

  f32x16 acc0 = {0.f,0.f,0.f,0.f,0.f,0.f,0.f,0.f,0.f,0.f,0.f,0.f,0.f,0.f,0.f,0.f};
  f32x16 acc1 = acc0;

  // staging assignment: thread -> (col sc, k-strip sk0..sk0+7)
  const int sc  = tid & 63;
  const int sk0 = (tid >> 6) * 8;
  const int sldsoff = sc * 64 + (((sk0 >> 3) ^ (sc & 7)) * 8);
  const float* bbase = B + (size_t)(k0 + sk0) * NHID + n0 + sc;

  float br[8];
  const int NT = KC >> 6;

  // prologue: stage tile 0
  {
    const float* p = bbase;
#pragma unroll
    for (int i = 0; i < 8; ++i) br[i] = p[(size_t)i * NHID];
    short8 hv;
#pragma unroll
    for (int i = 0; i < 8; ++i) hv[i] = (short)f2bf(br[i]);
    *reinterpret_cast<short8*>(&Blds[0][sldsoff]) = hv;
  }
  __syncthreads();

  const unsigned short* abase = A + (size_t)(wm * 64 + l31) * lda + k0 + hi * 8;
  const int bcol = wn * 32 + l31;
  int cur = 0;

  for (int t = 0; t < NT; ++t) {
    // A fragments FIRST (oldest in vmcnt FIFO -> their wait leaves B in flight)
    short8 a0[4], a1[4];
    const unsigned short* at = abase + (size_t)t * 64;
#pragma unroll
    for (int kk = 0; kk < 4; ++kk) {
      a0[kk] = *reinterpret_cast<const short8*>(at + kk * 16);
      a1[kk] = *reinterpret_cast<const short8*>(at + (size_t)32 * lda + kk * 16);
    }
    // issue next tile's B loads (consumed at bottom of this iteration)
    if (t + 1 < NT) {
      const float* p = bbase + (size_t)(t + 1) * 64 * NHID;
#pragma unroll
      for (int i = 0; i < 8; ++i) br[i] = p[(size_t)i * NHID];
    }
    // B fragments from LDS + MFMA
#pragma unroll
    for (int kk = 0; kk < 4; ++kk) {
      int chunk = kk * 2 + hi;
      short8 bfr = *reinterpret_cast<const short8*>(
          &Blds[cur][bcol * 64 + ((chunk ^ (bcol & 7)) * 8)]);
      acc0 = __builtin_amdgcn_mfma_f32_32x32x16_bf16(a0[kk], bfr, acc0, 0, 0, 0);
      acc1 = __builtin_amdgcn_mfma_f32_32x32x16_bf16(a1[kk], bfr, acc1, 0, 0, 0);
    }
    // write next tile into the other LDS buffer
    if (t + 1 < NT) {
      short8 hv;
#pragma unroll
      for (int i = 0; i < 8; ++i) hv[i] = (short)f2bf(br[i]);
      *reinterpret_cast<short8*>(&Blds[cur ^ 1][sldsoff]) = hv;
    }
    __syncthreads();
    cur ^= 1;
  }

  // epilogue
  const int col = n0 + wn * 32 + l31;
  const float bvs = FINAL ? bias[col] : 0.f;
#pragma unroll
  for (int reg = 0; reg < 16; ++reg) {
    int rowoff = (reg & 3) + 8 * (reg >> 2) + 4 * hi;
    int row0 = wm * 64 + rowoff;
    int row1 = row0 + 32;
    if (FINAL) {
      float v0 = acc0[reg] + bvs; v0 = v0 > 0.f ? v0 : 0.f;
      float v1 = acc1[reg] + bvs; v1 = v1 > 0.f ? v1 : 0.f;
      Cf[(size_t)row0 * NHID + col] = f2bf(v0);
      Cf[(size_t)row1 * NHID + col] = f2bf(v1);
    } else {
      float* base = Cp + (size_t)ks * 256 * NHID;
      base[(size_t)row0 * NHID + col] = acc0[reg];
      base[(size_t)row1 * NHID + col] = acc1[reg];
    }
  }
}

// ---------------- reduce K-split partials: h2 = relu(sum_s part + bias) -> bf16 ----------------
__global__ void reduce_h2(const float* __restrict__ part, const float* __restrict__ bias,
                          unsigned short* __restrict__ h2, int S) {
  size_t g = ((size_t)blockIdx.x * 256 + threadIdx.x) * 4;   // elem idx in [256][NHID]
  int c = (int)(g % NHID);
  float4 s = *reinterpret_cast<const float4*>(part + g);
  for (int k = 1; k < S; ++k) {
    float4 p = *reinterpret_cast<const float4*>(part + (size_t)k * 256 * NHID + g);
    s.x += p.x; s.y += p.y; s.z += p.z; s.w += p.w;
  }
  float4 b = *reinterpret_cast<const float4*>(bias + c);
  s.x += b.x; s.y += b.y; s.z += b.z; s.w += b.w;
  us4 o;
  o[0] = f2bf(s.x > 0.f ? s.x : 0.f);
  o[1] = f2bf(s.y > 0.f ? s.y : 0.f);
  o[2] = f2bf(s.z > 0.f ? s.z : 0.f);
  o[3] = f2bf(s.w > 0.f ? s.w : 0.f);
  *reinterpret_cast<us4*>(h2 + g) = o;
}

// ---------------- kernel: fold Wout [15872][992] -> Wv [15872][32] ----------------
__global__ void wv_fold(const float* __restrict__ Wout, float* __restrict__ Wv) {
  int g = blockIdx.x * 256 + threadIdx.x;   // < 15872*32
  int k = g >> 5, c = g & 31;
  const float* row = Wout + (size_t)k * 992;
  float s = 0.f;
#pragma unroll
  for (int o = 0; o < 32; ++o) {
    if (o == c) continue;
    int i = c < o ? c : o;
    int j = c < o ? o : c;
    int p = 31 * i - (i * (i - 1)) / 2 + (j - i - 1);
    s += row[2 * p + (c > o ? 1 : 0)];
  }
  Wv[g] = s;
}

// ---------------- kernel: votes partial = h2 @ Wv, K-split 32 ----------------
__global__ void votes_partial(const unsigned short* __restrict__ h2,
                              const float* __restrict__ Wv,
                              float* __restrict__ part) {
  int bm = blockIdx.x >> 5;        // 0..31 -> 8 rows each
  int ks = blockIdx.x & 31;        // K split
  int r  = bm * 8 + (threadIdx.x >> 5);
  int c  = threadIdx.x & 31;
  const unsigned short* hrow = h2 + (size_t)r * NHID + ks * 496;
  const float* wp = Wv + (size_t)(ks * 496) * 32 + c;
  float s = 0.f;
  for (int k0 = 0; k0 < 496; k0 += 8) {
    short8 hv = *reinterpret_cast<const short8*>(hrow + k0);
#pragma unroll
    for (int j = 0; j < 8; ++j)
      s += bf2f((unsigned short)hv[j]) * wp[(size_t)(k0 + j) * 32];
  }
  part[(size_t)(ks * 256 + r) * 32 + c] = s;
}

// ---------------- kernel: reduce partials + bias-fold ----------------
__global__ void votes_reduce(const float* __restrict__ part,
                             const float* __restrict__ bout,
                             float* __restrict__ out) {
  int g = blockIdx.x * 256 + threadIdx.x;  // < 8192
  int c = g & 31;
  float s = 0.f;
#pragma unroll
  for (int ks = 0; ks < 32; ++ks) s += part[(size_t)ks * 8192 + g];
  float bv = 0.f;
#pragma unroll
  for (int o = 0; o < 32; ++o) {
    if (o == c) continue;
    int i = c < o ? c : o;
    int j = c < o ? o : c;
    int p = 31 * i - (i * (i - 1)) / 2 + (j - i - 1);
    bv += bout[2 * p + (c > o ? 1 : 0)];
  }
  out[g] = s + bv;
}

extern "C" void kernel_launch(void* const* d_in, const int* in_sizes, int n_in,
                              void* d_out, int out_size, void* d_ws, size_t ws_size,
                              hipStream_t stream) {
  const float* x    = (const float*)d_in[0];
  const float* W1   = (const float*)d_in[1];
  const float* b1   = (const float*)d_in[2];
  const float* W2   = (const float*)d_in[3];
  const float* b2   = (const float*)d_in[4];
  const float* Wout = (const float*)d_in[5];
  const float* bout = (const float*)d_in[6];
  float* out = (float*)d_out;

  char* ws = (char*)d_ws;
  unsigned short* xb = (unsigned short*)(ws);                       // 256*512*2   = 262144
  unsigned short* h1 = (unsigned short*)(ws + 262144);              // 256*15872*2 = 8126464
  unsigned short* h2 = (unsigned short*)(ws + 8388608);             // 8126464
  float*          Wv = (float*)(ws + 16515072);                     // 15872*32*4  = 2031616
  float*        part = (float*)(ws + 18546688);                     // 32*256*32*4 = 1048576
  float*       part2 = (float*)(ws + 19595264);                     // S*256*NHID*4

  const size_t PART1 = (size_t)256 * NHID * 4;   // 16,252,928 per K-chunk
  int S = 1;
  if (ws_size >= 19595264ull + 4 * PART1) S = 4;
  else if (ws_size >= 19595264ull + 2 * PART1) S = 2;

  hipLaunchKernelGGL(cvt_x, dim3(128), dim3(256), 0, stream, x, xb);
  // GEMM1: K=512, final (bias+relu->bf16)
  hipLaunchKernelGGL((gemm_k<true>), dim3(248, 1), dim3(512), 0, stream,
                     xb, 512, 512, W1, b1, h1, (float*)nullptr);
  // GEMM2: K=15872 split S ways
  if (S > 1) {
    hipLaunchKernelGGL((gemm_k<false>), dim3(248, S), dim3(512), 0, stream,
                       h1, NHID, NHID / S, W2, (const float*)nullptr,
                       (unsigned short*)nullptr, part2);
    hipLaunchKernelGGL(reduce_h2, dim3(3968), dim3(256), 0, stream, part2, b2, h2, S);
  } else {
    hipLaunchKernelGGL((gemm_k<true>), dim3(248, 1), dim3(512), 0, stream,
                       h1, NHID, NHID, W2, b2, h2, (float*)nullptr);
  }
  hipLaunchKernelGGL(wv_fold,       dim3(1984), dim3(256), 0, stream, Wout, Wv);
  hipLaunchKernelGGL(votes_partial, dim3(1024), dim3(256), 0, stream, h2, Wv, part);
  hipLaunchKernelGGL(votes_reduce,  dim3(32),   dim3(256), 0, stream, part, bout, out);
}

// Round 5
// 457.037 us; speedup vs baseline: 2.1425x; 1.7377x over previous
//
#include <hip/hip_runtime.h>

using short8 = __attribute__((ext_vector_type(8))) short;
using f32x16 = __attribute__((ext_vector_type(16))) float;
using f32x4  = __attribute__((ext_vector_type(4))) float;
using us4    = __attribute__((ext_vector_type(4))) unsigned short;

#define NHID 15872

__device__ __forceinline__ unsigned short f2bf(float f) {
  unsigned u = __builtin_bit_cast(unsigned, f);
  u += 0x7fff + ((u >> 16) & 1);          // RNE
  return (unsigned short)(u >> 16);
}
__device__ __forceinline__ float bf2f(unsigned short h) {
  return __builtin_bit_cast(float, ((unsigned)h) << 16);
}
__device__ __forceinline__ int swz(int col, int c) {
  return (c ^ (col & 7) ^ ((col >> 3) & 7)) & 7;
}

// ---------------- kernel 0: x fp32 -> bf16 ----------------
__global__ void cvt_x(const float* __restrict__ x, unsigned short* __restrict__ xb) {
  int i = (blockIdx.x * 256 + threadIdx.x) * 4;
  float4 v = *reinterpret_cast<const float4*>(x + i);
  us4 o;
  o[0] = f2bf(v.x); o[1] = f2bf(v.y); o[2] = f2bf(v.z); o[3] = f2bf(v.w);
  *reinterpret_cast<us4*>(xb + i) = o;
}

// ---------------- main GEMM v5 ----------------
// BM=256 (all M), BN=128, BK=64. 8 waves, wave w = rows w*32..w*32+31 x all 128 cols.
// B staged f32->bf16 into double-buffered swizzled LDS via dwordx4 loads.
// A fragments direct from global (L2-resident), no N-duplication.
// grid = (124 N-tiles, S K-chunks), block 512.

#define LOADB(R, T) do { _Pragma("unroll") \
  for (int r_ = 0; r_ < 4; ++r_) \
    R[r_] = *reinterpret_cast<const f32x4*>(bbase + ((size_t)(T) * 64 + r_) * NHID); \
} while (0)

#define CVTW(R, BUF) do { _Pragma("unroll") \
  for (int c2_ = 0; c2_ < 4; ++c2_) { \
    int col_ = cq * 4 + c2_; \
    int wa_ = col_ * 64 + swz(col_, kst >> 1) * 8 + (kst & 1) * 4; \
    us4 o_; \
    _Pragma("unroll") \
    for (int r_ = 0; r_ < 4; ++r_) o_[r_] = f2bf(R[r_][c2_]); \
    *reinterpret_cast<us4*>(&Blds[BUF][wa_]) = o_; \
  } \
} while (0)

#define MFMAP(BUF, T) do { \
  const unsigned short* at_ = abase + (size_t)(T) * 64; \
  short8 a_[4]; \
  _Pragma("unroll") \
  for (int ks_ = 0; ks_ < 4; ++ks_) \
    a_[ks_] = *reinterpret_cast<const short8*>(at_ + ks_ * 16); \
  _Pragma("unroll") \
  for (int ks_ = 0; ks_ < 4; ++ks_) { \
    int c_ = ks_ * 2 + hi; \
    short8 b0_ = *reinterpret_cast<const short8*>(&Blds[BUF][(l31) * 64 + swz(l31, c_) * 8]); \
    short8 b1_ = *reinterpret_cast<const short8*>(&Blds[BUF][(32 + l31) * 64 + swz(32 + l31, c_) * 8]); \
    short8 b2_ = *reinterpret_cast<const short8*>(&Blds[BUF][(64 + l31) * 64 + swz(64 + l31, c_) * 8]); \
    short8 b3_ = *reinterpret_cast<const short8*>(&Blds[BUF][(96 + l31) * 64 + swz(96 + l31, c_) * 8]); \
    acc0 = __builtin_amdgcn_mfma_f32_32x32x16_bf16(a_[ks_], b0_, acc0, 0, 0, 0); \
    acc1 = __builtin_amdgcn_mfma_f32_32x32x16_bf16(a_[ks_], b1_, acc1, 0, 0, 0); \
    acc2 = __builtin_amdgcn_mfma_f32_32x32x16_bf16(a_[ks_], b2_, acc2, 0, 0, 0); \
    acc3 = __builtin_amdgcn_mfma_f32_32x32x16_bf16(a_[ks_], b3_, acc3, 0, 0, 0); \
  } \
} while (0)

template<bool FINAL>
__global__ __launch_bounds__(512, 4)
void gemm_v5(const unsigned short* __restrict__ A, int lda, int KC,
             const float* __restrict__ B, const float* __restrict__ bias,
             unsigned short* __restrict__ Cf, float* __restrict__ Cp)
{
  __shared__ short Blds[2][128 * 64];   // [buf][col][64k] bf16, swizzled
  const int tid  = threadIdx.x;
  const int n0   = blockIdx.x * 128;
  const int ks0  = blockIdx.y;
  const int k0   = ks0 * KC;
  const int lane = tid & 63;
  const int w    = tid >> 6;
  const int l31  = lane & 31;
  const int hi   = lane >> 5;

  f32x16 acc0 = {}, acc1 = {}, acc2 = {}, acc3 = {};

  // B stager: cq = col-quad (cols cq*4..+3), kst = k-strip (k rows kst*4..+3)
  const int cq  = tid & 31;
  const int kst = tid >> 5;
  const float* bbase = B + (size_t)(k0 + kst * 4) * NHID + n0 + cq * 4;
  // A: wave w rows w*32+l31, k-halves by hi
  const unsigned short* abase = A + (size_t)(w * 32 + l31) * lda + k0 + hi * 8;

  f32x4 rA[4], rB[4];
  const int NT = KC >> 6;   // even (>=4) for all our K

  // prologue: tiles 0,1
  LOADB(rA, 0);
  LOADB(rB, 1);
  CVTW(rA, 0);
  __syncthreads();

  for (int t = 0; t < NT - 2; t += 2) {
    LOADB(rA, t + 2);
    MFMAP(0, t);
    CVTW(rB, 1);
    __syncthreads();
    LOADB(rB, t + 3);
    MFMAP(1, t + 1);
    CVTW(rA, 0);
    __syncthreads();
  }
  MFMAP(0, NT - 2);
  CVTW(rB, 1);
  __syncthreads();
  MFMAP(1, NT - 1);

  // epilogue: verified C/D mapping: col = lane&31 (+32*cblk), row = (reg&3)+8*(reg>>2)+4*hi
#define STOREC(ACC, CBLK) do { \
    int col_ = n0 + (CBLK) * 32 + l31; \
    if (FINAL) { \
      float bv_ = bias[col_]; \
      _Pragma("unroll") \
      for (int reg_ = 0; reg_ < 16; ++reg_) { \
        int row_ = w * 32 + (reg_ & 3) + 8 * (reg_ >> 2) + 4 * hi; \
        float v_ = ACC[reg_] + bv_; v_ = v_ > 0.f ? v_ : 0.f; \
        Cf[(size_t)row_ * NHID + col_] = f2bf(v_); \
      } \
    } else { \
      float* base_ = Cp + (size_t)ks0 * 256 * NHID; \
      _Pragma("unroll") \
      for (int reg_ = 0; reg_ < 16; ++reg_) { \
        int row_ = w * 32 + (reg_ & 3) + 8 * (reg_ >> 2) + 4 * hi; \
        base_[(size_t)row_ * NHID + col_] = ACC[reg_]; \
      } \
    } \
  } while (0)

  STOREC(acc0, 0);
  STOREC(acc1, 1);
  STOREC(acc2, 2);
  STOREC(acc3, 3);
#undef STOREC
}

// ---------------- reduce K-split partials: h2 = relu(sum_s part + bias) -> bf16 ----------------
__global__ void reduce_h2(const float* __restrict__ part, const float* __restrict__ bias,
                          unsigned short* __restrict__ h2, int S) {
  size_t g = ((size_t)blockIdx.x * 256 + threadIdx.x) * 4;
  int c = (int)(g % NHID);
  float4 s = *reinterpret_cast<const float4*>(part + g);
  for (int k = 1; k < S; ++k) {
    float4 p = *reinterpret_cast<const float4*>(part + (size_t)k * 256 * NHID + g);
    s.x += p.x; s.y += p.y; s.z += p.z; s.w += p.w;
  }
  float4 b = *reinterpret_cast<const float4*>(bias + c);
  s.x += b.x; s.y += b.y; s.z += b.z; s.w += b.w;
  us4 o;
  o[0] = f2bf(s.x > 0.f ? s.x : 0.f);
  o[1] = f2bf(s.y > 0.f ? s.y : 0.f);
  o[2] = f2bf(s.z > 0.f ? s.z : 0.f);
  o[3] = f2bf(s.w > 0.f ? s.w : 0.f);
  *reinterpret_cast<us4*>(h2 + g) = o;
}

// ---------------- fold Wout [15872][992] -> Wv [15872][32] ----------------
__global__ void wv_fold(const float* __restrict__ Wout, float* __restrict__ Wv) {
  int g = blockIdx.x * 256 + threadIdx.x;
  int k = g >> 5, c = g & 31;
  const float* row = Wout + (size_t)k * 992;
  float s = 0.f;
#pragma unroll
  for (int o = 0; o < 32; ++o) {
    if (o == c) continue;
    int i = c < o ? c : o;
    int j = c < o ? o : c;
    int p = 31 * i - (i * (i - 1)) / 2 + (j - i - 1);
    s += row[2 * p + (c > o ? 1 : 0)];
  }
  Wv[g] = s;
}

// ---------------- votes partial = h2 @ Wv, K-split 32 ----------------
__global__ void votes_partial(const unsigned short* __restrict__ h2,
                              const float* __restrict__ Wv,
                              float* __restrict__ part) {
  int bm = blockIdx.x >> 5;
  int ks = blockIdx.x & 31;
  int r  = bm * 8 + (threadIdx.x >> 5);
  int c  = threadIdx.x & 31;
  const unsigned short* hrow = h2 + (size_t)r * NHID + ks * 496;
  const float* wp = Wv + (size_t)(ks * 496) * 32 + c;
  float s = 0.f;
  for (int k0 = 0; k0 < 496; k0 += 8) {
    short8 hv = *reinterpret_cast<const short8*>(hrow + k0);
#pragma unroll
    for (int j = 0; j < 8; ++j)
      s += bf2f((unsigned short)hv[j]) * wp[(size_t)(k0 + j) * 32];
  }
  part[(size_t)(ks * 256 + r) * 32 + c] = s;
}

// ---------------- reduce votes + bias-fold ----------------
__global__ void votes_reduce(const float* __restrict__ part,
                             const float* __restrict__ bout,
                             float* __restrict__ out) {
  int g = blockIdx.x * 256 + threadIdx.x;
  int c = g & 31;
  float s = 0.f;
#pragma unroll
  for (int ks = 0; ks < 32; ++ks) s += part[(size_t)ks * 8192 + g];
  float bv = 0.f;
#pragma unroll
  for (int o = 0; o < 32; ++o) {
    if (o == c) continue;
    int i = c < o ? c : o;
    int j = c < o ? o : c;
    int p = 31 * i - (i * (i - 1)) / 2 + (j - i - 1);
    bv += bout[2 * p + (c > o ? 1 : 0)];
  }
  out[g] = s + bv;
}

extern "C" void kernel_launch(void* const* d_in, const int* in_sizes, int n_in,
                              void* d_out, int out_size, void* d_ws, size_t ws_size,
                              hipStream_t stream) {
  const float* x    = (const float*)d_in[0];
  const float* W1   = (const float*)d_in[1];
  const float* b1   = (const float*)d_in[2];
  const float* W2   = (const float*)d_in[3];
  const float* b2   = (const float*)d_in[4];
  const float* Wout = (const float*)d_in[5];
  const float* bout = (const float*)d_in[6];
  float* out = (float*)d_out;

  char* ws = (char*)d_ws;
  unsigned short* xb = (unsigned short*)(ws);                       // 262144
  unsigned short* h1 = (unsigned short*)(ws + 262144);              // 8126464
  unsigned short* h2 = (unsigned short*)(ws + 8388608);             // 8126464
  float*          Wv = (float*)(ws + 16515072);                     // 2031616
  float*        part = (float*)(ws + 18546688);                     // 1048576
  float*       part2 = (float*)(ws + 19595264);                     // S*256*NHID*4

  const size_t PART1 = (size_t)256 * NHID * 4;
  int S = 1;
  if (ws_size >= 19595264ull + 4 * PART1) S = 4;
  else if (ws_size >= 19595264ull + 2 * PART1) S = 2;

  hipLaunchKernelGGL(cvt_x, dim3(128), dim3(256), 0, stream, x, xb);
  hipLaunchKernelGGL((gemm_v5<true>), dim3(124, 1), dim3(512), 0, stream,
                     xb, 512, 512, W1, b1, h1, (float*)nullptr);
  if (S > 1) {
    hipLaunchKernelGGL((gemm_v5<false>), dim3(124, S), dim3(512), 0, stream,
                       h1, NHID, NHID / S, W2, (const float*)nullptr,
                       (unsigned short*)nullptr, part2);
    hipLaunchKernelGGL(reduce_h2, dim3(3968), dim3(256), 0, stream, part2, b2, h2, S);
  } else {
    hipLaunchKernelGGL((gemm_v5<true>), dim3(124, 1), dim3(512), 0, stream,
                       h1, NHID, NHID, W2, b2, h2, (float*)nullptr);
  }
  hipLaunchKernelGGL(wv_fold,       dim3(1984), dim3(256), 0, stream, Wout, Wv);
  hipLaunchKernelGGL(votes_partial, dim3(1024), dim3(256), 0, stream, h2, Wv, part);
  hipLaunchKernelGGL(votes_reduce,  dim3(32),   dim3(256), 0, stream, part, bout, out);
}